// Round 1
// baseline (1233.743 us; speedup 1.0000x reference)
//
#include <hip/hip_runtime.h>
#include <math.h>

// ISTFT: B=16, T=2048, 513 bins, FFT=1024, HOP=256.
// time[n]*N = sum_f wR[f]*re[f]*cos(2pi n f/N) - sum_f 2*im[f]*sin(2pi n f/N)
//   for n in [0,512];  time[N-n]*N = C[n] + S[n]  (n in [1,511])
// windowed = time * hann/norm ; overlap-add at hop 256 via atomics.

#define BATCH   16
#define TFR     2048
#define NBINS   513
#define FFTN    1024
#define HOP     256
#define OUTLEN  ((TFR - 1) * HOP + FFTN)   // 525056

#define TM 64   // frames per block
#define TN 64   // n-values per block
#define TK 32   // f per K-step
#define NKT ((NBINS + TK - 1) / TK)        // 17

#define STEP 6.1359231515e-3f              // 2*pi/1024

__global__ __launch_bounds__(256)
void istft_frames(const float2* __restrict__ stfts, float* __restrict__ out)
{
    __shared__ float2 As[TK][TM + 2];   // [f][frame] = (wR*re, 2*im); +2 pad keeps rows 16B-aligned
    __shared__ float2 Bs[TN][TK + 1];   // [n][f] = (cos, sin); odd stride -> 2-way (free) on b64
    __shared__ float  cosT[FFTN];
    __shared__ float  sinT[FFTN];

    const int tid = threadIdx.x;
    const int m0  = blockIdx.x * TM;
    const int n0  = blockIdx.y * TN;

    // mod-1024 trig tables (per block; 4 sincosf/thread, negligible)
    for (int i = tid; i < FFTN; i += 256) {
        float s, c;
        sincosf((float)i * STEP, &s, &c);
        cosT[i] = c;
        sinT[i] = s;
    }

    const int nl = tid & 63;        // n within tile
    const int mg = tid >> 6;        // wave id: frames mg*16 .. mg*16+15
    const int n  = n0 + nl;

    float accC[16], accS[16];
    #pragma unroll
    for (int j = 0; j < 16; ++j) { accC[j] = 0.f; accS[j] = 0.f; }

    const int fl = tid & 31;
    const int mh = tid >> 5;

    __syncthreads();   // trig tables ready

    for (int kt = 0; kt < NKT; ++kt) {
        const int f = kt * TK + fl;

        // stage A: 64 frames x 32 f, coalesced float2 loads, zero-fill f>=513
        #pragma unroll
        for (int r = 0; r < 8; ++r) {
            const int ml = r * 8 + mh;
            float2 v = make_float2(0.f, 0.f);
            if (f < NBINS) {
                const float2 t = stfts[(m0 + ml) * NBINS + f];
                const float wr = (f == 0 || f == NBINS - 1) ? 1.f : 2.f;
                v = make_float2(t.x * wr, t.y * 2.f);
            }
            As[fl][ml] = v;
        }
        // build B from mod-1024 tables: cos/sin(2pi*n*f/1024)
        #pragma unroll
        for (int r = 0; r < 8; ++r) {
            const int bl  = r * 8 + mh;
            const int idx = ((n0 + bl) * f) & (FFTN - 1);
            Bs[bl][fl] = make_float2(cosT[idx], sinT[idx]);
        }
        __syncthreads();

        #pragma unroll 8
        for (int ff = 0; ff < TK; ++ff) {
            const float2 b = Bs[nl][ff];
            #pragma unroll
            for (int j = 0; j < 16; j += 2) {
                // wave-uniform (broadcast) b128: frames j, j+1 at bin ff
                const float4 a = *reinterpret_cast<const float4*>(&As[ff][mg * 16 + j]);
                accC[j]     += a.x * b.x;
                accS[j]     += a.y * b.y;
                accC[j + 1] += a.z * b.x;
                accS[j + 1] += a.w * b.y;
            }
        }
        __syncthreads();
    }

    // epilogue: window (symmetric: w[1024-n] == w[n]), 1/N, overlap-add
    if (n < NBINS) {
        const float syn   = (0.5f - 0.5f * cosf((float)n * STEP)) * 0.8660254f;
        const float scale = syn * (1.0f / (float)FFTN);
        const int   l2    = FFTN - n;
        const bool  hasB  = (n >= 1 && n <= FFTN / 2 - 1);
        #pragma unroll
        for (int j = 0; j < 16; ++j) {
            const int m = m0 + mg * 16 + j;
            const int b = m >> 11;          // / TFR
            const int t = m & (TFR - 1);
            float* obase = out + (size_t)b * OUTLEN + t * HOP;
            atomicAdd(&obase[n], (accC[j] - accS[j]) * scale);
            if (hasB) atomicAdd(&obase[l2], (accC[j] + accS[j]) * scale);
        }
    }
}

extern "C" void kernel_launch(void* const* d_in, const int* in_sizes, int n_in,
                              void* d_out, int out_size, void* d_ws, size_t ws_size,
                              hipStream_t stream)
{
    const float2* stfts = reinterpret_cast<const float2*>(d_in[0]);
    float* out = reinterpret_cast<float*>(d_out);

    hipMemsetAsync(d_out, 0, (size_t)out_size * sizeof(float), stream);

    dim3 grid(BATCH * TFR / TM, (NBINS + TN - 1) / TN);   // (512, 9)
    istft_frames<<<grid, dim3(256), 0, stream>>>(stfts, out);
}

// Round 2
// 242.793 us; speedup vs baseline: 5.0814x; 5.0814x over previous
//
#include <hip/hip_runtime.h>
#include <hip/hip_bf16.h>
#include <math.h>

// ISTFT as bf16 MFMA GEMM:
//   windowed[m][n] = sum_k A[m][k] * B[k][n],  m in [0,32768), n in [0,1024), K=1026
//   A = stfts viewed as [32768][1026] fp32 (re,im interleaved) -> bf16 on the fly
//   B[2f][n]   =  wR(f) * cos(2*pi*n*f/1024) * syn[n]/1024   (wR = 1 for f=0,512 else 2)
//   B[2f+1][n] = -2     * sin(2*pi*n*f/1024) * syn[n]/1024
//   out[b][t*256 + n] += windowed[m=b*2048+t][n]   (overlap-add, 4 contributions/sample)

#define BATCH  16
#define TFR    2048
#define FFTN   1024
#define HOP    256
#define OUTLEN 525056                 // (2048-1)*256 + 1024
#define M_TOT  (BATCH * TFR)          // 32768
#define K_TOT  1026
#define K_PAD  1056                   // 33 * 32
#define NKT    33
#define BM     128
#define BN     128
#define BK     32

#define STEP 6.13592315e-3f           // 2*pi/1024

typedef __attribute__((ext_vector_type(4))) float f32x4;
typedef __attribute__((ext_vector_type(8))) short bf16x8;

// ---- build B[n][k] (row-major in n, k contiguous; row stride K_PAD) ----
__global__ __launch_bounds__(256)
void build_B(__hip_bfloat16* __restrict__ Bg)
{
    const int n = blockIdx.x;
    const float window = 0.5f - 0.5f * cosf((float)n * STEP);
    const float scale  = window * 0.8660254f * (1.0f / (float)FFTN); // syn[n]/N

    for (int k = threadIdx.x; k < K_PAD; k += 256) {
        float val = 0.f;
        if (k < K_TOT) {
            const int f = k >> 1;
            const float ang = (float)((n * f) & (FFTN - 1)) * STEP;
            float s, c;
            sincosf(ang, &s, &c);
            if ((k & 1) == 0) {
                const float wr = (f == 0 || f == 512) ? 1.f : 2.f;
                val = wr * c * scale;
            } else {
                val = -2.f * s * scale;
            }
        }
        Bg[(size_t)n * K_PAD + k] = __float2bfloat16(val);
    }
}

// ---- main GEMM + overlap-add ----
__global__ __launch_bounds__(256)
void istft_gemm(const float* __restrict__ A, const __hip_bfloat16* __restrict__ Bg,
                float* __restrict__ out)
{
    __shared__ __hip_bfloat16 Asl[BM * BK];   // [m][k], row stride 32 (64 B)
    __shared__ __hip_bfloat16 Bsl[BN * BK];   // [n][k], row stride 32

    const int tid  = threadIdx.x;
    const int m0   = blockIdx.x * BM;
    const int n0   = blockIdx.y * BN;
    const int lane = tid & 63;
    const int wave = tid >> 6;
    const int wm   = wave >> 1;               // 0..1  (m half)
    const int wn   = wave & 1;                // 0..1  (n half)

    f32x4 acc[4][4] = {};

    // A-staging map: thread (sr, sc) loads float2 (one complex bin) per round
    const int sr = tid >> 4;                  // 0..15
    const int sc = tid & 15;                  // 0..15 -> bin within k-tile
    // B-staging map: thread -> row t>>1, 32B half (t&1)
    const int br = tid >> 1;                  // 0..127
    const int bc = (tid & 1) * 16;            // element offset 0 / 16

    // frag read map
    const int fr = lane & 15;
    const int fk = (lane >> 4) * 8;

    for (int kt = 0; kt < NKT; ++kt) {
        // stage A: 128 rows x 16 complex bins, fp32 -> bf16
        #pragma unroll
        for (int r = 0; r < 8; ++r) {
            const int m    = r * 16 + sr;
            const int fidx = kt * 16 + sc;    // complex bin index
            float2 v = make_float2(0.f, 0.f);
            if (fidx <= 512)
                v = *reinterpret_cast<const float2*>(A + (size_t)(m0 + m) * K_TOT + fidx * 2);
            __hip_bfloat162 h = __float22bfloat162_rn(v);
            *reinterpret_cast<__hip_bfloat162*>(&Asl[m * BK + sc * 2]) = h;
        }
        // stage B: 128 rows x 32 k (bf16), two 16B vector copies per thread
        {
            const __hip_bfloat16* bg = Bg + (size_t)(n0 + br) * K_PAD + kt * BK + bc;
            *reinterpret_cast<bf16x8*>(&Bsl[br * BK + bc]) =
                *reinterpret_cast<const bf16x8*>(bg);
            *reinterpret_cast<bf16x8*>(&Bsl[br * BK + bc + 8]) =
                *reinterpret_cast<const bf16x8*>(bg + 8);
        }
        __syncthreads();

        bf16x8 a[4], b[4];
        #pragma unroll
        for (int mi = 0; mi < 4; ++mi)
            a[mi] = *reinterpret_cast<const bf16x8*>(&Asl[(wm * 64 + mi * 16 + fr) * BK + fk]);
        #pragma unroll
        for (int ni = 0; ni < 4; ++ni)
            b[ni] = *reinterpret_cast<const bf16x8*>(&Bsl[(wn * 64 + ni * 16 + fr) * BK + fk]);

        #pragma unroll
        for (int mi = 0; mi < 4; ++mi)
            #pragma unroll
            for (int ni = 0; ni < 4; ++ni)
                acc[mi][ni] = __builtin_amdgcn_mfma_f32_16x16x32_bf16(
                    a[mi], b[ni], acc[mi][ni], 0, 0, 0);

        __syncthreads();
    }

    // epilogue: C/D layout col = lane&15, row = (lane>>4)*4 + j  [m89 verified]
    const int cr = (lane >> 4) * 4;
    const int cc = lane & 15;
    #pragma unroll
    for (int mi = 0; mi < 4; ++mi) {
        #pragma unroll
        for (int ni = 0; ni < 4; ++ni) {
            const int n = n0 + wn * 64 + ni * 16 + cc;
            #pragma unroll
            for (int j = 0; j < 4; ++j) {
                const int m = m0 + wm * 64 + mi * 16 + cr + j;
                const int bb = m >> 11;          // / 2048
                const int t  = m & (TFR - 1);
                atomicAdd(out + (size_t)bb * OUTLEN + t * HOP + n, acc[mi][ni][j]);
            }
        }
    }
}

extern "C" void kernel_launch(void* const* d_in, const int* in_sizes, int n_in,
                              void* d_out, int out_size, void* d_ws, size_t ws_size,
                              hipStream_t stream)
{
    const float* A = reinterpret_cast<const float*>(d_in[0]);
    float* out = reinterpret_cast<float*>(d_out);
    __hip_bfloat16* Bg = reinterpret_cast<__hip_bfloat16*>(d_ws);  // 1024*1056*2 B = 2.1 MB

    hipMemsetAsync(d_out, 0, (size_t)out_size * sizeof(float), stream);

    build_B<<<dim3(FFTN), dim3(256), 0, stream>>>(Bg);

    dim3 grid(M_TOT / BM, FFTN / BN);   // (256, 8)
    istft_gemm<<<grid, dim3(256), 0, stream>>>(A, Bg, out);
}

// Round 3
// 230.691 us; speedup vs baseline: 5.3480x; 1.0525x over previous
//
#include <hip/hip_runtime.h>
#include <hip/hip_bf16.h>
#include <math.h>

// ISTFT as bf16 MFMA GEMM (m97 structure: global_load_lds staging, 128x128x32):
//   windowed[m][n] = sum_k A[m][k] * B[k][n],  m in [0,32768), n in [0,1024), K=1026(->1056)
//   A = stfts [32768][1026] fp32 (re,im interleaved), pre-converted to bf16 in d_ws
//   B[2f][n]   =  wR(f) * cos(2*pi*n*f/1024) * syn[n]/1024   (wR = 1 for f=0,512 else 2)
//   B[2f+1][n] = -2     * sin(2*pi*n*f/1024) * syn[n]/1024
//   out[b][t*256 + n] += windowed[m=b*2048+t][n]   (overlap-add, 4 contributions/sample)

#define BATCH  16
#define TFR    2048
#define FFTN   1024
#define HOP    256
#define OUTLEN 525056                 // (2048-1)*256 + 1024
#define M_TOT  (BATCH * TFR)          // 32768
#define K_TOT  1026
#define K_PAD  1056                   // 33 * 32
#define NKT    33
#define BM     128
#define BN     128
#define BK     32
#define CHUNKS_PER_ROW (K_PAD / 8)    // 132

#define STEP 6.13592315e-3f           // 2*pi/1024

typedef __attribute__((ext_vector_type(4))) float f32x4;
typedef __attribute__((ext_vector_type(8))) short bf16x8;

__device__ __forceinline__ void load_lds16(const void* g, void* l)
{
    __builtin_amdgcn_global_load_lds((const __attribute__((address_space(1))) void*)g,
                                     (__attribute__((address_space(3))) void*)l,
                                     16, 0, 0);
}

// ---- build B[n][k] (row-major in n, k contiguous; row stride K_PAD) ----
__global__ __launch_bounds__(256)
void build_B(__hip_bfloat16* __restrict__ Bg)
{
    const int n = blockIdx.x;
    const float window = 0.5f - 0.5f * cosf((float)n * STEP);
    const float scale  = window * 0.8660254f * (1.0f / (float)FFTN); // syn[n]/N

    for (int k = threadIdx.x; k < K_PAD; k += 256) {
        float val = 0.f;
        if (k < K_TOT) {
            const int f = k >> 1;
            const float ang = (float)((n * f) & (FFTN - 1)) * STEP;
            float s, c;
            sincosf(ang, &s, &c);
            if ((k & 1) == 0) {
                const float wr = (f == 0 || f == 512) ? 1.f : 2.f;
                val = wr * c * scale;
            } else {
                val = -2.f * s * scale;
            }
        }
        Bg[(size_t)n * K_PAD + k] = __float2bfloat16(val);
    }
}

// ---- pre-convert A: fp32 [m][1026] -> bf16 [m][1056] (zero-padded) ----
__global__ __launch_bounds__(256)
void convert_A(const float* __restrict__ A, __hip_bfloat16* __restrict__ Ab)
{
    const int idx = blockIdx.x * 256 + threadIdx.x;      // one 8-elem chunk each
    if (idx >= M_TOT * CHUNKS_PER_ROW) return;
    const int m  = idx / CHUNKS_PER_ROW;
    const int k8 = (idx - m * CHUNKS_PER_ROW) * 8;

    const float* src = A + (size_t)m * K_TOT + k8;
    union { bf16x8 v; __hip_bfloat162 h[4]; } u;
    #pragma unroll
    for (int j = 0; j < 8; j += 2) {
        float2 t = make_float2(0.f, 0.f);
        if (k8 + j < K_TOT)            // K_TOT even: pair fully valid or fully invalid
            t = *reinterpret_cast<const float2*>(src + j);
        u.h[j >> 1] = __float22bfloat162_rn(t);
    }
    *reinterpret_cast<bf16x8*>(Ab + (size_t)m * K_PAD + k8) = u.v;   // 16B aligned
}

// ---- main GEMM (global_load_lds staging) + overlap-add ----
__global__ __launch_bounds__(256)
void istft_gemm_lds(const __hip_bfloat16* __restrict__ Ab,
                    const __hip_bfloat16* __restrict__ Bg,
                    float* __restrict__ out)
{
    __shared__ __hip_bfloat16 Asl[BM * BK];   // [m][k], linear, row stride 32 (64 B)
    __shared__ __hip_bfloat16 Bsl[BN * BK];   // [n][k], linear

    const int tid  = threadIdx.x;
    const int m0   = blockIdx.x * BM;
    const int n0   = blockIdx.y * BN;
    const int lane = tid & 63;
    const int wave = tid >> 6;
    const int wm   = wave >> 1;               // m half
    const int wn   = wave & 1;                // n half

    f32x4 acc[4][4] = {};

    // staging map: thread tid covers elements [tid*8, tid*8+8) of a 64-row chunk
    //   row = tid>>2 (0..63), col = (tid&3)*8 ; LDS dest byte = tid*16 (= wave*1024 + lane*16)
    const int sm = tid >> 2;
    const int sk = (tid & 3) * 8;

    const int fr = lane & 15;
    const int fk = (lane >> 4) * 8;

    const __hip_bfloat16* ga0 = Ab + (size_t)(m0 + sm) * K_PAD + sk;
    const __hip_bfloat16* ga1 = Ab + (size_t)(m0 + 64 + sm) * K_PAD + sk;
    const __hip_bfloat16* gb0 = Bg + (size_t)(n0 + sm) * K_PAD + sk;
    const __hip_bfloat16* gb1 = Bg + (size_t)(n0 + 64 + sm) * K_PAD + sk;

    for (int kt = 0; kt < NKT; ++kt) {
        const int ko = kt * BK;
        load_lds16(ga0 + ko, Asl + tid * 8);
        load_lds16(ga1 + ko, Asl + 2048 + tid * 8);
        load_lds16(gb0 + ko, Bsl + tid * 8);
        load_lds16(gb1 + ko, Bsl + 2048 + tid * 8);
        __syncthreads();

        bf16x8 a[4], b[4];
        #pragma unroll
        for (int mi = 0; mi < 4; ++mi)
            a[mi] = *reinterpret_cast<const bf16x8*>(&Asl[(wm * 64 + mi * 16 + fr) * BK + fk]);
        #pragma unroll
        for (int ni = 0; ni < 4; ++ni)
            b[ni] = *reinterpret_cast<const bf16x8*>(&Bsl[(wn * 64 + ni * 16 + fr) * BK + fk]);

        #pragma unroll
        for (int mi = 0; mi < 4; ++mi)
            #pragma unroll
            for (int ni = 0; ni < 4; ++ni)
                acc[mi][ni] = __builtin_amdgcn_mfma_f32_16x16x32_bf16(
                    a[mi], b[ni], acc[mi][ni], 0, 0, 0);

        __syncthreads();
    }

    // epilogue: C/D layout col = lane&15, row = (lane>>4)*4 + j  [m89 verified]
    const int cr = (lane >> 4) * 4;
    const int cc = lane & 15;
    #pragma unroll
    for (int mi = 0; mi < 4; ++mi) {
        #pragma unroll
        for (int ni = 0; ni < 4; ++ni) {
            const int n = n0 + wn * 64 + ni * 16 + cc;
            #pragma unroll
            for (int j = 0; j < 4; ++j) {
                const int m = m0 + wm * 64 + mi * 16 + cr + j;
                const int bb = m >> 11;          // / 2048
                const int t  = m & (TFR - 1);
                atomicAdd(out + (size_t)bb * OUTLEN + t * HOP + n, acc[mi][ni][j]);
            }
        }
    }
}

// ---- fallback GEMM (R2: reg-staged, reads fp32 A directly) ----
__global__ __launch_bounds__(256)
void istft_gemm_fb(const float* __restrict__ A, const __hip_bfloat16* __restrict__ Bg,
                   float* __restrict__ out)
{
    __shared__ __hip_bfloat16 Asl[BM * BK];
    __shared__ __hip_bfloat16 Bsl[BN * BK];

    const int tid  = threadIdx.x;
    const int m0   = blockIdx.x * BM;
    const int n0   = blockIdx.y * BN;
    const int lane = tid & 63;
    const int wave = tid >> 6;
    const int wm   = wave >> 1;
    const int wn   = wave & 1;

    f32x4 acc[4][4] = {};

    const int sr = tid >> 4;
    const int sc = tid & 15;
    const int br = tid >> 1;
    const int bc = (tid & 1) * 16;
    const int fr = lane & 15;
    const int fk = (lane >> 4) * 8;

    for (int kt = 0; kt < NKT; ++kt) {
        #pragma unroll
        for (int r = 0; r < 8; ++r) {
            const int m    = r * 16 + sr;
            const int fidx = kt * 16 + sc;
            float2 v = make_float2(0.f, 0.f);
            if (fidx <= 512)
                v = *reinterpret_cast<const float2*>(A + (size_t)(m0 + m) * K_TOT + fidx * 2);
            __hip_bfloat162 h = __float22bfloat162_rn(v);
            *reinterpret_cast<__hip_bfloat162*>(&Asl[m * BK + sc * 2]) = h;
        }
        {
            const __hip_bfloat16* bg = Bg + (size_t)(n0 + br) * K_PAD + kt * BK + bc;
            *reinterpret_cast<bf16x8*>(&Bsl[br * BK + bc]) =
                *reinterpret_cast<const bf16x8*>(bg);
            *reinterpret_cast<bf16x8*>(&Bsl[br * BK + bc + 8]) =
                *reinterpret_cast<const bf16x8*>(bg + 8);
        }
        __syncthreads();

        bf16x8 a[4], b[4];
        #pragma unroll
        for (int mi = 0; mi < 4; ++mi)
            a[mi] = *reinterpret_cast<const bf16x8*>(&Asl[(wm * 64 + mi * 16 + fr) * BK + fk]);
        #pragma unroll
        for (int ni = 0; ni < 4; ++ni)
            b[ni] = *reinterpret_cast<const bf16x8*>(&Bsl[(wn * 64 + ni * 16 + fr) * BK + fk]);

        #pragma unroll
        for (int mi = 0; mi < 4; ++mi)
            #pragma unroll
            for (int ni = 0; ni < 4; ++ni)
                acc[mi][ni] = __builtin_amdgcn_mfma_f32_16x16x32_bf16(
                    a[mi], b[ni], acc[mi][ni], 0, 0, 0);

        __syncthreads();
    }

    const int cr = (lane >> 4) * 4;
    const int cc = lane & 15;
    #pragma unroll
    for (int mi = 0; mi < 4; ++mi) {
        #pragma unroll
        for (int ni = 0; ni < 4; ++ni) {
            const int n = n0 + wn * 64 + ni * 16 + cc;
            #pragma unroll
            for (int j = 0; j < 4; ++j) {
                const int m = m0 + wm * 64 + mi * 16 + cr + j;
                const int bb = m >> 11;
                const int t  = m & (TFR - 1);
                atomicAdd(out + (size_t)bb * OUTLEN + t * HOP + n, acc[mi][ni][j]);
            }
        }
    }
}

extern "C" void kernel_launch(void* const* d_in, const int* in_sizes, int n_in,
                              void* d_out, int out_size, void* d_ws, size_t ws_size,
                              hipStream_t stream)
{
    const float* A = reinterpret_cast<const float*>(d_in[0]);
    float* out = reinterpret_cast<float*>(d_out);

    const size_t abBytes = (size_t)M_TOT * K_PAD * sizeof(__hip_bfloat16); // 69.2 MB
    const size_t bBytes  = (size_t)FFTN * K_PAD * sizeof(__hip_bfloat16);  // 2.1 MB

    hipMemsetAsync(d_out, 0, (size_t)out_size * sizeof(float), stream);

    dim3 grid(M_TOT / BM, FFTN / BN);   // (256, 8)

    if (ws_size >= abBytes + bBytes) {
        __hip_bfloat16* Ab = reinterpret_cast<__hip_bfloat16*>(d_ws);
        __hip_bfloat16* Bg = reinterpret_cast<__hip_bfloat16*>((char*)d_ws + abBytes);
        build_B<<<dim3(FFTN), dim3(256), 0, stream>>>(Bg);
        const int nChunks = M_TOT * CHUNKS_PER_ROW;            // 4,325,376
        convert_A<<<dim3((nChunks + 255) / 256), dim3(256), 0, stream>>>(A, Ab);
        istft_gemm_lds<<<grid, dim3(256), 0, stream>>>(Ab, Bg, out);
    } else {
        __hip_bfloat16* Bg = reinterpret_cast<__hip_bfloat16*>(d_ws);
        build_B<<<dim3(FFTN), dim3(256), 0, stream>>>(Bg);
        istft_gemm_fb<<<grid, dim3(256), 0, stream>>>(A, Bg, out);
    }
}

// Round 5
// 229.968 us; speedup vs baseline: 5.3648x; 1.0031x over previous
//
#include <hip/hip_runtime.h>
#include <math.h>

// ISTFT via packed real inverse FFT + LDS overlap-add.
//   B=16, T=2048, 513 bins, FFT=1024, HOP=256, out = 16 x 525056 (= 2051*256).
//   x[n] = (1/1024) sum_f Y[f] e^{+2pi i n f/1024}, Y hermitian-extended with
//   DC/Nyquist imaginary parts ZEROED (reference multiplies them by sin(0)/sin(pi n)=0).
//   Pack: z[m] = x[2m] + i x[2m+1] = (1/1024) * unnormalized IDFT_512(Z)[m] (x2 folded),
//         Z[k] = (Y[k]+C[k]) + i e^{2pi i k/1024} (Y[k]-C[k]),
//         C[0] = Y[512] (real), C[k] = conj(Y[512-k]) for k>=1.
//   IDFT_512: Stockham autosort, 4 radix-4 passes + final radix-2 (fused with
//   window + OLA).  windowed[n] = x[n] * (0.5-0.5cos(2pi n/1024)) * (sqrt(3)/2).
//   Block owns 32 output rows of 256 (8192 samples), processes frames
//   T0-3 .. T0+31, accumulates in LDS, plain-stores its exclusive region.

#define BATCH  16
#define TFR    2048
#define NB     513
#define FFTN   1024
#define HOP    256
#define OUTLEN 525056
#define TROWS  2051
#define OWN    32
#define NBLK   65                    // ceil(2051/32)
#define OLALEN (OWN * HOP)           // 8192 floats

#define FIDX(i) ((i) + ((i) >> 3))   // LDS pad: +1 slot every 8

#define TWO_PI_N 6.135923151542565e-3f   // 2*pi/1024
#define WSCALE   8.456302966727588e-4f   // (sqrt(3)/2) / 1024

__device__ __forceinline__ float2 cmul(float2 a, float2 w) {
    return make_float2(a.x * w.x - a.y * w.y, a.x * w.y + a.y * w.x);
}

__device__ __forceinline__ void radix4_pass(const float2* __restrict__ src,
                                            float2* __restrict__ dst,
                                            const float2* __restrict__ T,
                                            int lane, int l2s, int step)
{
    #pragma unroll
    for (int r = 0; r < 2; ++r) {
        const int u = lane + 64 * r;          // u in [0,128)
        const int p = u >> l2s;
        const int q = u & ((1 << l2s) - 1);
        const float2 a0 = src[FIDX(u)];
        const float2 a1 = src[FIDX(u + 128)];
        const float2 a2 = src[FIDX(u + 256)];
        const float2 a3 = src[FIDX(u + 384)];
        // inverse radix-4 butterfly (i * (x,y) = (-y, x))
        const float2 s02 = make_float2(a0.x + a2.x, a0.y + a2.y);
        const float2 d02 = make_float2(a0.x - a2.x, a0.y - a2.y);
        const float2 s13 = make_float2(a1.x + a3.x, a1.y + a3.y);
        const float2 d13 = make_float2(a1.x - a3.x, a1.y - a3.y);
        const float2 A0 = make_float2(s02.x + s13.x, s02.y + s13.y);
        const float2 A1 = make_float2(d02.x - d13.y, d02.y + d13.x);
        const float2 A2 = make_float2(s02.x - s13.x, s02.y - s13.y);
        const float2 A3 = make_float2(d02.x + d13.y, d02.y - d13.x);
        const float2 w1 = T[FIDX(p * step)];
        const float2 w2 = cmul(w1, w1);
        const float2 w3 = cmul(w2, w1);
        const int d = q + ((4 * p) << l2s);   // q + s*4p
        dst[FIDX(d)]                  = A0;
        dst[FIDX(d + (1 << l2s))]     = cmul(A1, w1);
        dst[FIDX(d + (2 << l2s))]     = cmul(A2, w2);
        dst[FIDX(d + (3 << l2s))]     = cmul(A3, w3);
    }
    asm volatile("s_waitcnt lgkmcnt(0)" ::: "memory");
}

__global__ __launch_bounds__(256)
void istft_fft(const float2* __restrict__ stfts, float* __restrict__ out)
{
    __shared__ float2 T[FIDX(1023) + 2];              // trig: e^{+2pi i k/1024}
    __shared__ float2 fbuf[8][FIDX(512) + 4];         // per-wave ping-pong (580)
    __shared__ __align__(16) float ola[OLALEN];

    const int tid  = threadIdx.x;
    const int lane = tid & 63;
    const int wave = tid >> 6;

    const int b  = blockIdx.x / NBLK;
    const int ib = blockIdx.x - b * NBLK;
    const int T0 = ib * OWN;

    for (int i = tid; i < FFTN; i += 256) {
        float s, c;
        sincosf((float)i * TWO_PI_N, &s, &c);
        T[FIDX(i)] = make_float2(c, s);
    }
    for (int i = tid; i < OLALEN / 4; i += 256)
        reinterpret_cast<float4*>(ola)[i] = make_float4(0.f, 0.f, 0.f, 0.f);
    __syncthreads();

    const int tmin = max(0, T0 - 3);
    const int tmax = min(TFR - 1, T0 + OWN - 1);
    const int F    = tmax - tmin + 1;

    float2* bA = fbuf[wave * 2 + 0];
    float2* bB = fbuf[wave * 2 + 1];

    for (int fi = wave; fi < F; fi += 4) {
        const int t = tmin + fi;
        const float2* Xg = stfts + (size_t)(b * TFR + t) * NB;

        // stage X[0..512] into bB (coalesced 8B/lane)
        #pragma unroll
        for (int r = 0; r < 8; ++r)
            bB[FIDX(lane + 64 * r)] = Xg[lane + 64 * r];
        if (lane == 0) bB[FIDX(512)] = Xg[512];
        asm volatile("s_waitcnt vmcnt(0) lgkmcnt(0)" ::: "memory");

        // hermitian pack -> Z in bA.
        // k==0 uses bins 0 & 512, whose IMAG parts the reference drops
        // (multiplied by sin(0) / sin(pi n) = 0): zero them here.
        #pragma unroll
        for (int r = 0; r < 8; ++r) {
            const int k = lane + 64 * r;
            const float2 X  = bB[FIDX(k)];
            const int   pk  = (k == 0) ? 512 : 512 - k;
            const float2 Cr = bB[FIDX(pk)];
            const float  Xy = (k == 0) ? 0.f : X.y;
            const float  cy = (k == 0) ? 0.f : -Cr.y;
            const float2 S  = make_float2(X.x + Cr.x, Xy + cy);
            const float2 D  = make_float2(X.x - Cr.x, Xy - cy);
            const float2 W  = T[FIDX(k)];
            const float  ex = W.x * D.x - W.y * D.y;
            const float  ey = W.x * D.y + W.y * D.x;
            bA[FIDX(k)] = make_float2(S.x - ey, S.y + ex);
        }
        asm volatile("s_waitcnt lgkmcnt(0)" ::: "memory");

        // 4 radix-4 Stockham passes: A->B->A->B->A
        radix4_pass(bA, bB, T, lane, 0, 2);
        radix4_pass(bB, bA, T, lane, 2, 8);
        radix4_pass(bA, bB, T, lane, 4, 32);
        radix4_pass(bB, bA, T, lane, 6, 128);

        // final radix-2 fused with window + OLA scatter
        const int base = (t - T0) * HOP;              // may be negative
        #pragma unroll
        for (int r = 0; r < 4; ++r) {
            const int u = lane + 64 * r;              // u in [0,256)
            const float2 a  = bA[FIDX(u)];
            const float2 bv = bA[FIDX(u + 256)];
            const float2 zl = make_float2(a.x + bv.x, a.y + bv.y);  // z[u]
            const float2 zh = make_float2(a.x - bv.x, a.y - bv.y);  // z[u+256]
            const float  c0 = T[FIDX(2 * u)].x;       // cos(2pi(2u)/1024)
            const float  c1 = T[FIDX(2 * u + 1)].x;   // cos(2pi(2u+1)/1024)
            const float  w0 = (0.5f - 0.5f * c0) * WSCALE;   // n = 2u
            const float  w1 = (0.5f - 0.5f * c1) * WSCALE;   // n = 2u+1
            const float  w2 = (0.5f + 0.5f * c0) * WSCALE;   // n = 2u+512
            const float  w3 = (0.5f + 0.5f * c1) * WSCALE;   // n = 2u+513
            const int i0 = base + 2 * u;
            const int i2 = i0 + 512;
            if ((unsigned)i0       < OLALEN) atomicAdd(&ola[i0],     zl.x * w0);
            if ((unsigned)(i0 + 1) < OLALEN) atomicAdd(&ola[i0 + 1], zl.y * w1);
            if ((unsigned)i2       < OLALEN) atomicAdd(&ola[i2],     zh.x * w2);
            if ((unsigned)(i2 + 1) < OLALEN) atomicAdd(&ola[i2 + 1], zh.y * w3);
        }
    }

    __syncthreads();

    // plain-store exclusive region (every out element written exactly once)
    const int ownRows = min(OWN, TROWS - T0);
    const int total4  = ownRows * (HOP / 4);
    float4* og = reinterpret_cast<float4*>(out + (size_t)b * OUTLEN + (size_t)T0 * HOP);
    const float4* ol = reinterpret_cast<const float4*>(ola);
    for (int i = tid; i < total4; i += 256)
        og[i] = ol[i];
}

extern "C" void kernel_launch(void* const* d_in, const int* in_sizes, int n_in,
                              void* d_out, int out_size, void* d_ws, size_t ws_size,
                              hipStream_t stream)
{
    const float2* stfts = reinterpret_cast<const float2*>(d_in[0]);
    float* out = reinterpret_cast<float*>(d_out);

    istft_fft<<<dim3(BATCH * NBLK), dim3(256), 0, stream>>>(stfts, out);
}